// Round 11
// baseline (252.841 us; speedup 1.0000x reference)
//
#include <hip/hip_runtime.h>
#include <stdint.h>

#define D_ 256
#define NQ_ 512
#define NK_ 512
#define NP_ (NQ_*NK_)

typedef __attribute__((ext_vector_type(8))) __bf16 bf16x8;
typedef __attribute__((ext_vector_type(4))) float f32x4;

__device__ __forceinline__ unsigned short f2bf(float f) {
  unsigned u = __builtin_bit_cast(unsigned, f);
  u += 0x7FFFu + ((u >> 16) & 1u);   // RNE
  return (unsigned short)(u >> 16);
}
__device__ __forceinline__ unsigned pk2(float a, float b) {
  return (unsigned)f2bf(a) | ((unsigned)f2bf(b) << 16);
}
__device__ __forceinline__ unsigned encf(float f) {  // order-preserving float->uint
  unsigned u = __builtin_bit_cast(unsigned, f);
  return (u & 0x80000000u) ? ~u : (u | 0x80000000u);
}
__device__ __forceinline__ float decf(unsigned e) {
  unsigned u = (e & 0x80000000u) ? (e ^ 0x80000000u) : ~e;
  return __builtin_bit_cast(float, u);
}

// ---------------- shared GEMM body (direct-from-global MFMA) ----------------
template<int EPI, int KTILES>
__device__ __forceinline__ void gemm_body(
    const unsigned short* __restrict__ A, int lda,
    const unsigned short* __restrict__ B, int ldb,
    const float* __restrict__ bias,
    void* __restrict__ Dst, int ldd, int nTilesN, int bid) {
  const int t = threadIdx.x, w = t >> 6, l = t & 63, l15 = l & 15, g = l >> 4;
  const int bm = bid / nTilesN, bn = bid % nTilesN;
  const int m0 = bm*64 + w*16, n0 = bn*64;
  const unsigned short* Ap = A + (size_t)(m0 + l15)*lda + g*8;
  const unsigned short* Bp = B + (size_t)(n0 + l15)*ldb + g*8;
  f32x4 acc[4];
  #pragma unroll
  for (int n = 0; n < 4; ++n) acc[n] = (f32x4){0.f,0.f,0.f,0.f};
  #pragma unroll 2
  for (int kk = 0; kk < KTILES; ++kk) {
    bf16x8 a = *(const bf16x8*)(Ap + kk*32);
    #pragma unroll
    for (int n = 0; n < 4; ++n) {
      bf16x8 b = *(const bf16x8*)(Bp + (size_t)n*16*ldb + kk*32);
      acc[n] = __builtin_amdgcn_mfma_f32_16x16x32_bf16(a, b, acc[n], 0, 0, 0);
    }
  }
  #pragma unroll
  for (int n = 0; n < 4; ++n) {
    const int col = n0 + n*16 + l15;
    const float bc = (EPI & 4) ? bias[col] : 0.f;
    #pragma unroll
    for (int r = 0; r < 4; ++r) {
      const int m = m0 + g*4 + r;
      float v = acc[n][r] + bc;
      if (EPI & 8) v += bias[m];
      if (EPI & 2) v = fmaxf(v, 0.f);
      if (EPI & 1) ((unsigned short*)Dst)[(size_t)m*ldd + col] = f2bf(v);
      else         ((float*)Dst)[(size_t)m*ldd + col] = v;
    }
  }
}

template<int EPI, int KTILES>
__global__ __launch_bounds__(256) void gemm_k(
    const unsigned short* __restrict__ A, int lda,
    const unsigned short* __restrict__ B, int ldb,
    const float* __restrict__ bias,
    void* __restrict__ Dst, int ldd, int nTilesN) {
  gemm_body<EPI, KTILES>(A, lda, B, ldb, bias, Dst, ldd, nTilesN, blockIdx.x);
}

// ---------------- kprep: init + conversions (Ab frag image w/ k-slot perm) + transposes
// blocks: 0 = init; [1,705) convert regions; [705,737) x->catT; [737,769) source->srcT
__global__ __launch_bounds__(256) void kprep(
    const unsigned* __restrict__ maskw, unsigned* __restrict__ wsMin,
    unsigned* __restrict__ wsFlag,
    const float* __restrict__ aW1, const float* __restrict__ source,
    const float* __restrict__ x, const float* __restrict__ mW1,
    const float* __restrict__ mW2,
    unsigned short* __restrict__ Ab, unsigned short* __restrict__ srcbf,
    unsigned short* __restrict__ mW1b, unsigned short* __restrict__ mW2b,
    unsigned short* __restrict__ aW1A, unsigned short* __restrict__ aW1B,
    unsigned short* __restrict__ catT, unsigned short* __restrict__ srcT) {
  __shared__ float tile[64][65];
  const int b = blockIdx.x, t = threadIdx.x;
  if (b == 0) {
    if (t < 64) {
      unsigned a01 = 1, af = 1;
      for (int i = 0; i < 4; ++i) {
        unsigned v = maskw[t*4 + i];
        a01 &= (v == 0u || v == 1u) ? 1u : 0u;
        af  &= (v == 0u || v == 0x3f800000u) ? 1u : 0u;
      }
      unsigned long long b01 = __ballot(a01 != 0), bf = __ballot(af != 0);
      if (t == 0) {
        *wsFlag = (b01 == ~0ull) ? 1u : ((bf == ~0ull) ? 2u : 0u);
        *wsMin = 0xFFFFFFFFu;
      }
    }
    return;
  }
  if (b < 705) {
    const int bb = b - 1;
    const float* src; unsigned short* dst;
    if (bb < 64) {
      // Ab: frag-linear image of aW1[:,512:768] for 1-wave kscores4.
      // frag f = kk*16+m (f = j>>9); lane li=(j>>3)&63; slot j0=j&7 (0 or 4 per ushort4)
      // row = m*16 + (li&15); ch = kk*32 + (j0<4 ? ga*4+j0.. : 16+ga*4+(j0-4)..), ga=li>>4
      int j = bb*1024 + t*4;
      int f = j >> 9, li = (j >> 3) & 63, j0 = j & 7;
      int kk = f >> 4, m = f & 15, ga = li >> 4;
      int row = m*16 + (li & 15);
      int chbase = kk*32 + ((j0 < 4) ? ga*4 : 16 + ga*4);
      src = aW1 + row*768 + 512 + chbase; dst = Ab + j;
    }
    else if (bb < 192)  { int j = (bb-64)*1024 + t*4;  src = source + j;    dst = srcbf + j; }
    else if (bb < 448)  { int j = (bb-192)*1024 + t*4; src = mW1 + j;       dst = mW1b + j; }
    else if (bb < 576)  { int j = (bb-448)*1024 + t*4; src = mW2 + j;       dst = mW2b + j; }
    else if (bb < 640)  { int j = (bb-576)*1024 + t*4; int e=j>>8, c=j&255; src = aW1 + e*768 + c;       dst = aW1A + j; }
    else                { int j = (bb-640)*1024 + t*4; int e=j>>8, c=j&255; src = aW1 + e*768 + 256 + c; dst = aW1B + j; }
    const float4 v = *(const float4*)src;
    ushort4 o; o.x=f2bf(v.x); o.y=f2bf(v.y); o.z=f2bf(v.z); o.w=f2bf(v.w);
    *(ushort4*)dst = o;
    return;
  }
  // tiled transpose f32 [256][512] -> bf16 [512][ldd]
  const float* src; unsigned short* dst; int ldd, bid;
  if (b < 737) { src = x;      dst = catT; ldd = 512; bid = b - 705; }
  else         { src = source; dst = srcT; ldd = 256; bid = b - 737; }
  const int bd = bid >> 3, bq = bid & 7;
  const int r = t >> 4, c4 = (t & 15) * 4;
  #pragma unroll
  for (int rr = 0; rr < 4; ++rr) {
    int dl = rr*16 + r;
    float4 v = *(const float4*)(src + (size_t)(bd*64 + dl)*512 + bq*64 + c4);
    tile[dl][c4+0] = v.x; tile[dl][c4+1] = v.y; tile[dl][c4+2] = v.z; tile[dl][c4+3] = v.w;
  }
  __syncthreads();
  #pragma unroll
  for (int rr = 0; rr < 4; ++rr) {
    int j = rr*16 + r;
    ushort4 o;
    o.x = f2bf(tile[c4+0][j]); o.y = f2bf(tile[c4+1][j]);
    o.z = f2bf(tile[c4+2][j]); o.w = f2bf(tile[c4+3][j]);
    *(ushort4*)(dst + (size_t)(bq*64 + j)*ldd + bd*64 + c4) = o;
  }
}

// ---------------- kprep2: Up and VmT GEMMs in one launch ----------------
__global__ __launch_bounds__(256) void kprep2(
    const unsigned short* __restrict__ catT, const unsigned short* __restrict__ aW1A,
    const float* __restrict__ ab1, float* __restrict__ Up,
    const unsigned short* __restrict__ srcT, const unsigned short* __restrict__ aW1B,
    float* __restrict__ VmT) {
  if (blockIdx.x < 32)
    gemm_body<4, 8>(catT, 512, aW1A, 256, ab1, (void*)Up, 256, 4, blockIdx.x);
  else
    gemm_body<0, 8>(srcT, 256, aW1B, 256, (const float*)nullptr, (void*)VmT, 256, 4, blockIdx.x - 32);
}

// ---------------- KB: 1-wave-per-block barrier-free scores GEMM ----------------
// 8192 blocks x 64 thr. Each wave: 32 pairs x 256 e, K=256 in 8 steps.
// B: 4x dwordx4/step (128B per channel row), ring-2 register pipeline.
// pair<->channel exchange in wave-private LDS (in-order DS, NO barriers at all).
// A-frags from frag-linear Ab (k-slot perm baked in; same perm on B via chmap).
__global__ __launch_bounds__(64, 2) void kscores4(
    const float* __restrict__ dist, const unsigned short* __restrict__ Ab,
    const float* __restrict__ Up, const float* __restrict__ VmT,
    const float* __restrict__ aW2, const float* __restrict__ ab2,
    float* __restrict__ outScores, unsigned* __restrict__ wsMin) {
  __shared__ __align__(16) unsigned short xch[32*40];   // [c2][40p pad] 2.5KB
  const int l = threadIdx.x;
  const int pl = l & 15, g = l >> 4;
  const int c2 = l >> 1, h = l & 1;

  const int pairTile = ((blockIdx.x & 7) << 10) + (blockIdx.x >> 3);  // XCD-bijective
  const int p0 = pairTile * 32;
  const int q = p0 >> 9;
  const int k0 = p0 & 511;          // key index of first pair (row-local)

  const float* dbase = dist + (size_t)c2 * NP_ + p0 + h * 16;

  // ring-2 B staging
  float4 bsA[4], bsB[4];
  #pragma unroll
  for (int j2 = 0; j2 < 4; ++j2) bsA[j2] = *(const float4*)(dbase + j2*4);
  #pragma unroll
  for (int j2 = 0; j2 < 4; ++j2) bsB[j2] = *(const float4*)(dbase + (size_t)32*NP_ + j2*4);

  // acc init = Up[q][e]
  f32x4 acc[16][2];
  #pragma unroll
  for (int m = 0; m < 16; ++m) {
    const float4 u = *(const float4*)(Up + q*256 + m*16 + g*4);
    acc[m][0][0]=u.x; acc[m][0][1]=u.y; acc[m][0][2]=u.z; acc[m][0][3]=u.w;
    acc[m][1][0]=u.x; acc[m][1][1]=u.y; acc[m][1][2]=u.z; acc[m][1][3]=u.w;
  }
  bf16x8 af[8];
  #pragma unroll
  for (int m = 0; m < 8; ++m)
    af[m] = *(const bf16x8*)(Ab + ((size_t)m << 9) + l*8);

  unsigned short* wp = xch + c2*40 + h*16;

#define KSTEP(KK, CUR)                                                          \
  {                                                                             \
    uint4 w0, w1;                                                               \
    w0.x = pk2(CUR[0].x, CUR[0].y); w0.y = pk2(CUR[0].z, CUR[0].w);             \
    w0.z = pk2(CUR[1].x, CUR[1].y); w0.w = pk2(CUR[1].z, CUR[1].w);             \
    w1.x = pk2(CUR[2].x, CUR[2].y); w1.y = pk2(CUR[2].z, CUR[2].w);             \
    w1.z = pk2(CUR[3].x, CUR[3].y); w1.w = pk2(CUR[3].z, CUR[3].w);             \
    *(uint4*)(wp)     = w0;                                                     \
    *(uint4*)(wp + 8) = w1;                                                     \
    if ((KK) + 2 < 8) {                                                         \
      const float* db2 = dbase + (size_t)((KK)+2)*32*NP_;                       \
      CUR[0] = *(const float4*)(db2);                                           \
      CUR[1] = *(const float4*)(db2 + 4);                                       \
      CUR[2] = *(const float4*)(db2 + 8);                                       \
      CUR[3] = *(const float4*)(db2 + 12);                                      \
    }                                                                           \
    bf16x8 bf0, bf1;                                                            \
    _Pragma("unroll")                                                           \
    for (int j = 0; j < 8; ++j) {                                               \
      const int ch = (j < 4) ? (g*4 + j) : (16 + g*4 + (j - 4));                \
      bf0[j] = __builtin_bit_cast(__bf16, xch[ch*40 + pl]);                     \
      bf1[j] = __builtin_bit_cast(__bf16, xch[ch*40 + 16 + pl]);                \
    }                                                                           \
    _Pragma("unroll")                                                           \
    for (int m = 0; m < 8; ++m) {                                               \
      acc[m][0] = __builtin_amdgcn_mfma_f32_16x16x32_bf16(af[m], bf0, acc[m][0], 0,0,0); \
      acc[m][1] = __builtin_amdgcn_mfma_f32_16x16x32_bf16(af[m], bf1, acc[m][1], 0,0,0); \
    }                                                                           \
    _Pragma("unroll")                                                           \
    for (int m = 0; m < 8; ++m)                                                 \
      af[m] = *(const bf16x8*)(Ab + ((size_t)((KK)*16 + 8 + m) << 9) + l*8);    \
    _Pragma("unroll")                                                           \
    for (int m = 0; m < 8; ++m) {                                               \
      acc[8+m][0] = __builtin_amdgcn_mfma_f32_16x16x32_bf16(af[m], bf0, acc[8+m][0], 0,0,0); \
      acc[8+m][1] = __builtin_amdgcn_mfma_f32_16x16x32_bf16(af[m], bf1, acc[8+m][1], 0,0,0); \
    }                                                                           \
    if ((KK) + 1 < 8) {                                                         \
      _Pragma("unroll")                                                         \
      for (int m = 0; m < 8; ++m)                                               \
        af[m] = *(const bf16x8*)(Ab + ((size_t)(((KK)+1)*16 + m) << 9) + l*8);  \
    }                                                                           \
  }

  KSTEP(0, bsA) KSTEP(1, bsB) KSTEP(2, bsA) KSTEP(3, bsB)
  KSTEP(4, bsA) KSTEP(5, bsB) KSTEP(6, bsA) KSTEP(7, bsB)
#undef KSTEP

  // ---- epilogue: score[p] = ab2 + sum_e aW2[e]*relu(acc + VmT[k][e]), k = key idx
  const float ab2v = ab2[0];
  float sc[2];
  #pragma unroll
  for (int n = 0; n < 2; ++n) {
    const int kidx = k0 + n*16 + pl;          // FIXED r10 bug: key index, not global pair
    float s2 = 0.f;
    #pragma unroll
    for (int m = 0; m < 16; ++m) {
      const float4 v4 = *(const float4*)(VmT + (size_t)kidx*256 + m*16 + g*4);
      const float4 a4 = *(const float4*)(aW2 + m*16 + g*4);
      s2 += a4.x * fmaxf(acc[m][n][0] + v4.x, 0.f);
      s2 += a4.y * fmaxf(acc[m][n][1] + v4.y, 0.f);
      s2 += a4.z * fmaxf(acc[m][n][2] + v4.z, 0.f);
      s2 += a4.w * fmaxf(acc[m][n][3] + v4.w, 0.f);
    }
    s2 += __shfl_xor(s2, 16);
    s2 += __shfl_xor(s2, 32);
    sc[n] = s2 + ab2v;
  }
  float mn = fminf(sc[0], sc[1]);
  #pragma unroll
  for (int off = 8; off; off >>= 1) mn = fminf(mn, __shfl_xor(mn, off));
  if (l < 16) {
    outScores[p0 + l]      = sc[0];
    outScores[p0 + 16 + l] = sc[1];
    if (l == 0) atomicMin(wsMin, encf(mn));
  }
}

// ---------------- KS: mask + softmax -> masked scores (out) + prob bf16 ----------------
__global__ __launch_bounds__(256) void ksoftmax(
    const void* __restrict__ maskp,
    const unsigned* __restrict__ wsMin, const unsigned* __restrict__ wsFlag,
    float* __restrict__ scores, unsigned short* __restrict__ prob) {
  __shared__ float srow[512];
  __shared__ float redl[8];
  const int t = threadIdx.x, w = t >> 6, l = t & 63;
  const int q = blockIdx.x;
  const float neg = decf(*wsMin) - 20.0f;
  const unsigned flag = *wsFlag;

  for (int k = t; k < 512; k += 256) {
    float raw = scores[q*512 + k];
    bool mv;
    if (flag == 1)      mv = ((const int*)maskp)[q*512 + k] != 0;
    else if (flag == 2) mv = ((const float*)maskp)[q*512 + k] != 0.f;
    else                mv = ((const unsigned char*)maskp)[q*512 + k] != 0;
    float ms = raw + (mv ? 0.f : neg);
    scores[q*512 + k] = ms;
    srow[k] = ms;
  }
  __syncthreads();
  float lm = fmaxf(srow[t], srow[t + 256]);
  #pragma unroll
  for (int off = 32; off; off >>= 1) lm = fmaxf(lm, __shfl_xor(lm, off));
  if (l == 0) redl[w] = lm;
  __syncthreads();
  float rmax = fmaxf(fmaxf(redl[0], redl[1]), fmaxf(redl[2], redl[3]));
  float e0 = __expf(srow[t] - rmax), e1 = __expf(srow[t + 256] - rmax);
  float ls = e0 + e1;
  #pragma unroll
  for (int off = 32; off; off >>= 1) ls += __shfl_xor(ls, off);
  if (l == 0) redl[4 + w] = ls;
  __syncthreads();
  float inv = 1.0f / (redl[4] + redl[5] + redl[6] + redl[7]);
  prob[q*512 + t]       = f2bf(e0 * inv);
  prob[q*512 + t + 256] = f2bf(e1 * inv);
}

extern "C" void kernel_launch(void* const* d_in, const int* in_sizes, int n_in,
                              void* d_out, int out_size, void* d_ws, size_t ws_size,
                              hipStream_t stream) {
  const float* x      = (const float*)d_in[0];
  const float* source = (const float*)d_in[1];
  const float* dist   = (const float*)d_in[2];
  const void*  mask   = (const void*)d_in[3];
  const float* aW1    = (const float*)d_in[4];
  const float* ab1    = (const float*)d_in[5];
  const float* aW2    = (const float*)d_in[6];
  const float* ab2    = (const float*)d_in[7];
  const float* mW1    = (const float*)d_in[8];
  const float* mb1    = (const float*)d_in[9];
  const float* mW2    = (const float*)d_in[10];
  const float* mb2    = (const float*)d_in[11];

  float* outMain = (float*)d_out;             // (1,256,512)
  float* scores  = outMain + 256*512;         // (1,512,512)

  char* ws = (char*)d_ws;
  unsigned* wsMin  = (unsigned*)ws;
  unsigned* wsFlag = wsMin + 1;
  unsigned short* Ab    = (unsigned short*)(ws + 1024);     // 128KB A frag-linear (perm'd)
  float*          Up    = (float*)(ws + 132096);            // 512x256 f32
  float*          VmT   = (float*)(ws + 656384);            // 512x256 f32 [k][e]
  unsigned short* srcbf = (unsigned short*)(ws + 1180672);  // 256x512 bf16 [d][k]
  unsigned short* srcT  = (unsigned short*)(ws + 1442816);  // 512x256 bf16 [k][c]
  unsigned short* mW1b  = (unsigned short*)(ws + 1704960);  // 512x512 bf16
  unsigned short* mW2b  = (unsigned short*)(ws + 2229248);  // 256x512 bf16
  unsigned short* aW1A  = (unsigned short*)(ws + 2491392);  // 256x256 bf16
  unsigned short* aW1B  = (unsigned short*)(ws + 2622464);  // 256x256 bf16
  unsigned short* catT  = (unsigned short*)(ws + 2753536);  // 512x512 bf16 [q][c]
  unsigned short* prob  = (unsigned short*)(ws + 3277824);  // 512x512 bf16 [q][k]
  unsigned short* h2T   = (unsigned short*)(ws + 3802112);  // 512x512 bf16 [q][o]

  hipLaunchKernelGGL(kprep, dim3(769), dim3(256), 0, stream,
                     (const unsigned*)mask, wsMin, wsFlag, aW1, source, x, mW1, mW2,
                     Ab, srcbf, mW1b, mW2b, aW1A, aW1B, catT, srcT);
  hipLaunchKernelGGL(kprep2, dim3(64), dim3(256), 0, stream,
                     catT, aW1A, ab1, Up, srcT, aW1B, VmT);
  hipLaunchKernelGGL(kscores4, dim3(8192), dim3(64), 0, stream,
                     dist, Ab, Up, VmT, aW2, ab2, scores, wsMin);
  hipLaunchKernelGGL(ksoftmax, dim3(512), dim3(256), 0, stream,
                     mask, wsMin, wsFlag, scores, prob);
  // msgT[q][d] = prob @ source^T  -> catT[:, 256:]
  hipLaunchKernelGGL((gemm_k<1, 16>), dim3(32), dim3(256), 0, stream,
                     prob, 512, srcbf, 512, (const float*)nullptr, (void*)(catT + 256), 512, 4);
  // h2T[q][o] = relu(catT @ mW1^T + mb1)
  hipLaunchKernelGGL((gemm_k<7, 16>), dim3(64), dim3(256), 0, stream,
                     catT, 512, mW1b, 512, mb1, (void*)h2T, 512, 8);
  // out[o2][q] = mW2 @ h2 + mb2
  hipLaunchKernelGGL((gemm_k<8, 16>), dim3(32), dim3(256), 0, stream,
                     mW2b, 512, h2T, 512, mb2, (void*)outMain, 512, 8);
}

// Round 12
// 241.450 us; speedup vs baseline: 1.0472x; 1.0472x over previous
//
#include <hip/hip_runtime.h>
#include <stdint.h>

#define D_ 256
#define NQ_ 512
#define NK_ 512
#define NP_ (NQ_*NK_)

typedef __attribute__((ext_vector_type(8))) __bf16 bf16x8;
typedef __attribute__((ext_vector_type(4))) float f32x4;

__device__ __forceinline__ unsigned short f2bf(float f) {
  unsigned u = __builtin_bit_cast(unsigned, f);
  u += 0x7FFFu + ((u >> 16) & 1u);   // RNE
  return (unsigned short)(u >> 16);
}
__device__ __forceinline__ unsigned pk2(float a, float b) {
  return (unsigned)f2bf(a) | ((unsigned)f2bf(b) << 16);
}
__device__ __forceinline__ unsigned encf(float f) {  // order-preserving float->uint
  unsigned u = __builtin_bit_cast(unsigned, f);
  return (u & 0x80000000u) ? ~u : (u | 0x80000000u);
}
__device__ __forceinline__ float decf(unsigned e) {
  unsigned u = (e & 0x80000000u) ? (e ^ 0x80000000u) : ~e;
  return __builtin_bit_cast(float, u);
}

// ---------------- shared GEMM body (direct-from-global MFMA) ----------------
template<int EPI, int KTILES>
__device__ __forceinline__ void gemm_body(
    const unsigned short* __restrict__ A, int lda,
    const unsigned short* __restrict__ B, int ldb,
    const float* __restrict__ bias,
    void* __restrict__ Dst, int ldd, int nTilesN, int bid) {
  const int t = threadIdx.x, w = t >> 6, l = t & 63, l15 = l & 15, g = l >> 4;
  const int bm = bid / nTilesN, bn = bid % nTilesN;
  const int m0 = bm*64 + w*16, n0 = bn*64;
  const unsigned short* Ap = A + (size_t)(m0 + l15)*lda + g*8;
  const unsigned short* Bp = B + (size_t)(n0 + l15)*ldb + g*8;
  f32x4 acc[4];
  #pragma unroll
  for (int n = 0; n < 4; ++n) acc[n] = (f32x4){0.f,0.f,0.f,0.f};
  #pragma unroll 2
  for (int kk = 0; kk < KTILES; ++kk) {
    bf16x8 a = *(const bf16x8*)(Ap + kk*32);
    #pragma unroll
    for (int n = 0; n < 4; ++n) {
      bf16x8 b = *(const bf16x8*)(Bp + (size_t)n*16*ldb + kk*32);
      acc[n] = __builtin_amdgcn_mfma_f32_16x16x32_bf16(a, b, acc[n], 0, 0, 0);
    }
  }
  #pragma unroll
  for (int n = 0; n < 4; ++n) {
    const int col = n0 + n*16 + l15;
    const float bc = (EPI & 4) ? bias[col] : 0.f;
    #pragma unroll
    for (int r = 0; r < 4; ++r) {
      const int m = m0 + g*4 + r;
      float v = acc[n][r] + bc;
      if (EPI & 8) v += bias[m];
      if (EPI & 2) v = fmaxf(v, 0.f);
      if (EPI & 1) ((unsigned short*)Dst)[(size_t)m*ldd + col] = f2bf(v);
      else         ((float*)Dst)[(size_t)m*ldd + col] = v;
    }
  }
}

template<int EPI, int KTILES>
__global__ __launch_bounds__(256) void gemm_k(
    const unsigned short* __restrict__ A, int lda,
    const unsigned short* __restrict__ B, int ldb,
    const float* __restrict__ bias,
    void* __restrict__ Dst, int ldd, int nTilesN) {
  gemm_body<EPI, KTILES>(A, lda, B, ldb, bias, Dst, ldd, nTilesN, blockIdx.x);
}

// ---------------- kprep: init + conversions (incl. frag-ordered Ab, r8 mapping) ----
// blocks: 0 = init; [1,705) convert regions; [705,737) x->catT; [737,769) source->srcT
__global__ __launch_bounds__(256) void kprep(
    const unsigned* __restrict__ maskw, unsigned* __restrict__ wsMin,
    unsigned* __restrict__ wsFlag,
    const float* __restrict__ aW1, const float* __restrict__ source,
    const float* __restrict__ x, const float* __restrict__ mW1,
    const float* __restrict__ mW2,
    unsigned short* __restrict__ Ab, unsigned short* __restrict__ srcbf,
    unsigned short* __restrict__ mW1b, unsigned short* __restrict__ mW2b,
    unsigned short* __restrict__ aW1A, unsigned short* __restrict__ aW1B,
    unsigned short* __restrict__ catT, unsigned short* __restrict__ srcT) {
  __shared__ float tile[64][65];
  const int b = blockIdx.x, t = threadIdx.x;
  if (b == 0) {
    if (t < 64) {
      unsigned a01 = 1, af = 1;
      for (int i = 0; i < 4; ++i) {
        unsigned v = maskw[t*4 + i];
        a01 &= (v == 0u || v == 1u) ? 1u : 0u;
        af  &= (v == 0u || v == 0x3f800000u) ? 1u : 0u;
      }
      unsigned long long b01 = __ballot(a01 != 0), bf = __ballot(af != 0);
      if (t == 0) {
        *wsFlag = (b01 == ~0ull) ? 1u : ((bf == ~0ull) ? 2u : 0u);
        *wsMin = 0xFFFFFFFFu;
      }
    }
    return;
  }
  if (b < 705) {
    const int bb = b - 1;
    const float* src; unsigned short* dst;
    if (bb < 64) {
      // Ab: A-fragment-linear image of aW1[:,512:768] (verified r8).
      int j = bb*1024 + t*4;
      int img = j >> 9, li = (j >> 3) & 63, i0 = j & 7;
      int row = ((img >> 2) & 3)*64 + (img & 3)*16 + (li & 15);
      int ch  = (img >> 4)*32 + (li >> 4)*8 + i0;
      src = aW1 + row*768 + 512 + ch; dst = Ab + j;
    }
    else if (bb < 192)  { int j = (bb-64)*1024 + t*4;  src = source + j;    dst = srcbf + j; }
    else if (bb < 448)  { int j = (bb-192)*1024 + t*4; src = mW1 + j;       dst = mW1b + j; }
    else if (bb < 576)  { int j = (bb-448)*1024 + t*4; src = mW2 + j;       dst = mW2b + j; }
    else if (bb < 640)  { int j = (bb-576)*1024 + t*4; int e=j>>8, c=j&255; src = aW1 + e*768 + c;       dst = aW1A + j; }
    else                { int j = (bb-640)*1024 + t*4; int e=j>>8, c=j&255; src = aW1 + e*768 + 256 + c; dst = aW1B + j; }
    const float4 v = *(const float4*)src;
    ushort4 o; o.x=f2bf(v.x); o.y=f2bf(v.y); o.z=f2bf(v.z); o.w=f2bf(v.w);
    *(ushort4*)dst = o;
    return;
  }
  // tiled transpose f32 [256][512] -> bf16 [512][ldd]
  const float* src; unsigned short* dst; int ldd, bid;
  if (b < 737) { src = x;      dst = catT; ldd = 512; bid = b - 705; }
  else         { src = source; dst = srcT; ldd = 256; bid = b - 737; }
  const int bd = bid >> 3, bq = bid & 7;
  const int r = t >> 4, c4 = (t & 15) * 4;
  #pragma unroll
  for (int rr = 0; rr < 4; ++rr) {
    int dl = rr*16 + r;
    float4 v = *(const float4*)(src + (size_t)(bd*64 + dl)*512 + bq*64 + c4);
    tile[dl][c4+0] = v.x; tile[dl][c4+1] = v.y; tile[dl][c4+2] = v.z; tile[dl][c4+3] = v.w;
  }
  __syncthreads();
  #pragma unroll
  for (int rr = 0; rr < 4; ++rr) {
    int j = rr*16 + r;
    ushort4 o;
    o.x = f2bf(tile[c4+0][j]); o.y = f2bf(tile[c4+1][j]);
    o.z = f2bf(tile[c4+2][j]); o.w = f2bf(tile[c4+3][j]);
    *(ushort4*)(dst + (size_t)(bq*64 + j)*ldd + bd*64 + c4) = o;
  }
}

// ---------------- kprep2: Up and VmT GEMMs in one launch (r9 verbatim) ----------------
__global__ __launch_bounds__(256) void kprep2(
    const unsigned short* __restrict__ catT, const unsigned short* __restrict__ aW1A,
    const float* __restrict__ ab1, float* __restrict__ Up,
    const unsigned short* __restrict__ srcT, const unsigned short* __restrict__ aW1B,
    float* __restrict__ VmT) {
  if (blockIdx.x < 32)
    gemm_body<4, 8>(catT, 512, aW1A, 256, ab1, (void*)Up, 256, 4, blockIdx.x);
  else
    gemm_body<0, 8>(srcT, 256, aW1B, 256, (const float*)nullptr, (void*)VmT, 256, 4, blockIdx.x - 32);
}

// ---------------- ktrans2: dist [c][p] f32 -> Bt frag-linear bf16 (linear streams) ----
// 4096 blocks x 256 thr: kk = bid&7 (32 channels), pgrp = bid>>3 (512 pairs).
// Read: 2KB contiguous per channel row. One barrier. Write: 4KB-contiguous images.
__global__ __launch_bounds__(256) void ktrans2(const float* __restrict__ dist,
                                               unsigned short* __restrict__ Bt) {
  __shared__ unsigned short lt[32][520];   // [ch][pair], pad 8 -> bank step 4 per ch
  const int t = threadIdx.x, w = t >> 6, l = t & 63;
  const int kk = blockIdx.x & 7;
  const int pgrp = blockIdx.x >> 3;
  const size_t pbase = (size_t)pgrp * 512;

  float4 v[16];
  #pragma unroll
  for (int i = 0; i < 8; ++i) {
    const float* src = dist + (size_t)(kk*32 + w*8 + i) * NP_ + pbase + l*8;
    v[2*i]   = *(const float4*)(src);
    v[2*i+1] = *(const float4*)(src + 4);
  }
  #pragma unroll
  for (int i = 0; i < 8; ++i) {
    uint4 o;
    o.x = pk2(v[2*i].x,   v[2*i].y);
    o.y = pk2(v[2*i].z,   v[2*i].w);
    o.z = pk2(v[2*i+1].x, v[2*i+1].y);
    o.w = pk2(v[2*i+1].z, v[2*i+1].w);
    *(uint4*)(&lt[w*8 + i][l*8]) = o;
  }
  __syncthreads();

  const int img = t >> 5, s = t & 31;
  unsigned short* dst = Bt + ((size_t)(pgrp*8 + img) * 8 + kk) * 2048;
  #pragma unroll
  for (int u8 = 0; u8 < 8; ++u8) {
    const int u = u8*32 + s;
    const int n = u >> 6, lidx = u & 63;
    const int g2 = lidx >> 4, pl = lidx & 15;
    const int p = img*64 + n*16 + pl;
    uint4 o;
    o.x = (unsigned)lt[g2*8+0][p] | ((unsigned)lt[g2*8+1][p] << 16);
    o.y = (unsigned)lt[g2*8+2][p] | ((unsigned)lt[g2*8+3][p] << 16);
    o.z = (unsigned)lt[g2*8+4][p] | ((unsigned)lt[g2*8+5][p] << 16);
    o.w = (unsigned)lt[g2*8+6][p] | ((unsigned)lt[g2*8+7][p] << 16);
    *(uint4*)(dst + (size_t)u*8) = o;
  }
}

// ---------------- kscores2: dense GEMM from frag-linear Bt/Ab (r8 + Up-init/VmT) ----
__global__ __launch_bounds__(256, 3) void kscores2(
    const unsigned short* __restrict__ Bt, const unsigned short* __restrict__ Ab,
    const float* __restrict__ Up, const float* __restrict__ VmT,
    const float* __restrict__ aW2, const float* __restrict__ ab2,
    float* __restrict__ outScores, unsigned* __restrict__ wsMin) {
  __shared__ __align__(16) unsigned char ldsB[2][4096];
  __shared__ float red[4][64];

  const int t = threadIdx.x, w = t >> 6, l = t & 63, l15 = l & 15, g = l >> 4;
  const int bid = blockIdx.x;
  const int pt = (bid & 7) * 512 + (bid >> 3);   // XCD-bijective
  const int p0 = pt * 64;
  const int q = p0 >> 9, k0 = p0 & 511;
  const unsigned short* img = Bt + (size_t)pt * 16384;

  // aW2 in regs; acc init = Up (replaces u_s)
  float aw[4][4];
  #pragma unroll
  for (int m = 0; m < 4; ++m) {
    const float4 a4 = *(const float4*)(aW2 + w*64 + m*16 + g*4);
    aw[m][0]=a4.x; aw[m][1]=a4.y; aw[m][2]=a4.z; aw[m][3]=a4.w;
  }
  const float ab2v = ab2[0];

  uint4 bs[2];
  bs[0] = *(const uint4*)(img + 0*2048 + t*8);
  bs[1] = *(const uint4*)(img + 1*2048 + t*8);
  bf16x8 af[2][4];
  #pragma unroll
  for (int m = 0; m < 4; ++m)
    af[0][m] = *(const bf16x8*)(Ab + (size_t)(w*4 + m)*512 + l*8);

  f32x4 acc[4][4];
  #pragma unroll
  for (int m = 0; m < 4; ++m) {
    const float4 u = *(const float4*)(Up + q*256 + w*64 + m*16 + g*4);
    #pragma unroll
    for (int n = 0; n < 4; ++n) {
      acc[m][n][0]=u.x; acc[m][n][1]=u.y; acc[m][n][2]=u.z; acc[m][n][3]=u.w;
    }
  }

  #pragma unroll
  for (int kk = 0; kk < 8; ++kk) {
    const int b = kk & 1;
    *(uint4*)(&ldsB[b][t*16]) = bs[b];                       // stage kk
    if (kk < 6) bs[b] = *(const uint4*)(img + (size_t)(kk+2)*2048 + t*8);
    if (kk < 7) {
      #pragma unroll
      for (int m = 0; m < 4; ++m)
        af[(kk+1)&1][m] = *(const bf16x8*)(Ab + (size_t)((kk+1)*16 + w*4 + m)*512 + l*8);
    }
    __builtin_amdgcn_sched_barrier(0);
    asm volatile("s_waitcnt lgkmcnt(0)" ::: "memory");
    __builtin_amdgcn_s_barrier();                            // no vmcnt drain
    __builtin_amdgcn_sched_barrier(0);
    bf16x8 bfrag[4];
    #pragma unroll
    for (int n = 0; n < 4; ++n)
      bfrag[n] = *(const bf16x8*)(&ldsB[b][n*1024 + l*16]);  // linear, conflict-free
    #pragma unroll
    for (int m = 0; m < 4; ++m)
      #pragma unroll
      for (int n = 0; n < 4; ++n)
        acc[m][n] = __builtin_amdgcn_mfma_f32_16x16x32_bf16(af[b][m], bfrag[n], acc[m][n], 0, 0, 0);
  }
  __syncthreads();

  // ---- epilogue: score[j] = ab2 + sum_e aW2[e]*relu(acc + VmT[j][e])
  float part[4];
  #pragma unroll
  for (int n = 0; n < 4; ++n) {
    const int j = k0 + n*16 + l15;
    float s2 = 0.f;
    #pragma unroll
    for (int m = 0; m < 4; ++m) {
      const float4 v4 = *(const float4*)(VmT + (size_t)j*256 + w*64 + m*16 + g*4);
      s2 += aw[m][0] * fmaxf(acc[m][n][0] + v4.x, 0.f);
      s2 += aw[m][1] * fmaxf(acc[m][n][1] + v4.y, 0.f);
      s2 += aw[m][2] * fmaxf(acc[m][n][2] + v4.z, 0.f);
      s2 += aw[m][3] * fmaxf(acc[m][n][3] + v4.w, 0.f);
    }
    s2 += __shfl_xor(s2, 16);
    s2 += __shfl_xor(s2, 32);
    part[n] = s2;
  }
  if (l < 16) {
    #pragma unroll
    for (int n = 0; n < 4; ++n) red[w][n*16 + l] = part[n];
  }
  __syncthreads();
  if (t < 64) {
    float s2 = red[0][t] + red[1][t] + red[2][t] + red[3][t] + ab2v;
    outScores[p0 + t] = s2;
    float mn = s2;
    #pragma unroll
    for (int off = 32; off; off >>= 1) mn = fminf(mn, __shfl_xor(mn, off));
    if (t == 0) atomicMin(wsMin, encf(mn));
  }
}

// ---------------- KS: mask + softmax -> masked scores (out) + prob bf16 ----------------
__global__ __launch_bounds__(256) void ksoftmax(
    const void* __restrict__ maskp,
    const unsigned* __restrict__ wsMin, const unsigned* __restrict__ wsFlag,
    float* __restrict__ scores, unsigned short* __restrict__ prob) {
  __shared__ float srow[512];
  __shared__ float redl[8];
  const int t = threadIdx.x, w = t >> 6, l = t & 63;
  const int q = blockIdx.x;
  const float neg = decf(*wsMin) - 20.0f;
  const unsigned flag = *wsFlag;

  for (int k = t; k < 512; k += 256) {
    float raw = scores[q*512 + k];
    bool mv;
    if (flag == 1)      mv = ((const int*)maskp)[q*512 + k] != 0;
    else if (flag == 2) mv = ((const float*)maskp)[q*512 + k] != 0.f;
    else                mv = ((const unsigned char*)maskp)[q*512 + k] != 0;
    float ms = raw + (mv ? 0.f : neg);
    scores[q*512 + k] = ms;
    srow[k] = ms;
  }
  __syncthreads();
  float lm = fmaxf(srow[t], srow[t + 256]);
  #pragma unroll
  for (int off = 32; off; off >>= 1) lm = fmaxf(lm, __shfl_xor(lm, off));
  if (l == 0) redl[w] = lm;
  __syncthreads();
  float rmax = fmaxf(fmaxf(redl[0], redl[1]), fmaxf(redl[2], redl[3]));
  float e0 = __expf(srow[t] - rmax), e1 = __expf(srow[t + 256] - rmax);
  float ls = e0 + e1;
  #pragma unroll
  for (int off = 32; off; off >>= 1) ls += __shfl_xor(ls, off);
  if (l == 0) redl[4 + w] = ls;
  __syncthreads();
  float inv = 1.0f / (redl[4] + redl[5] + redl[6] + redl[7]);
  prob[q*512 + t]       = f2bf(e0 * inv);
  prob[q*512 + t + 256] = f2bf(e1 * inv);
}

extern "C" void kernel_launch(void* const* d_in, const int* in_sizes, int n_in,
                              void* d_out, int out_size, void* d_ws, size_t ws_size,
                              hipStream_t stream) {
  const float* x      = (const float*)d_in[0];
  const float* source = (const float*)d_in[1];
  const float* dist   = (const float*)d_in[2];
  const void*  mask   = (const void*)d_in[3];
  const float* aW1    = (const float*)d_in[4];
  const float* ab1    = (const float*)d_in[5];
  const float* aW2    = (const float*)d_in[6];
  const float* ab2    = (const float*)d_in[7];
  const float* mW1    = (const float*)d_in[8];
  const float* mb1    = (const float*)d_in[9];
  const float* mW2    = (const float*)d_in[10];
  const float* mb2    = (const float*)d_in[11];

  float* outMain = (float*)d_out;             // (1,256,512)
  float* scores  = outMain + 256*512;         // (1,512,512)

  char* ws = (char*)d_ws;
  unsigned* wsMin  = (unsigned*)ws;
  unsigned* wsFlag = wsMin + 1;
  unsigned short* Ab    = (unsigned short*)(ws + 1024);     // 128KB A frag-linear
  float*          Up    = (float*)(ws + 132096);            // 512x256 f32
  float*          VmT   = (float*)(ws + 656384);            // 512x256 f32 [k][e]
  unsigned short* srcbf = (unsigned short*)(ws + 1180672);  // 256x512 bf16 [d][k]
  unsigned short* srcT  = (unsigned short*)(ws + 1442816);  // 512x256 bf16 [k][c]
  unsigned short* mW1b  = (unsigned short*)(ws + 1704960);  // 512x512 bf16
  unsigned short* mW2b  = (unsigned short*)(ws + 2229248);  // 256x512 bf16
  unsigned short* aW1A  = (unsigned short*)(ws + 2491392);  // 256x256 bf16
  unsigned short* aW1B  = (unsigned short*)(ws + 2622464);  // 256x256 bf16
  unsigned short* catT  = (unsigned short*)(ws + 2753536);  // 512x512 bf16 [q][c]
  unsigned short* prob  = (unsigned short*)(ws + 3277824);  // 512x512 bf16 [q][k]
  unsigned short* h2T   = (unsigned short*)(ws + 3802112);  // 512x512 bf16 [q][o]
  unsigned short* Bt    = (unsigned short*)(ws + 16*1024*1024); // 128MB frag-linear B

  hipLaunchKernelGGL(kprep, dim3(769), dim3(256), 0, stream,
                     (const unsigned*)mask, wsMin, wsFlag, aW1, source, x, mW1, mW2,
                     Ab, srcbf, mW1b, mW2b, aW1A, aW1B, catT, srcT);
  hipLaunchKernelGGL(kprep2, dim3(64), dim3(256), 0, stream,
                     catT, aW1A, ab1, Up, srcT, aW1B, VmT);
  hipLaunchKernelGGL(ktrans2, dim3(4096), dim3(256), 0, stream, dist, Bt);
  hipLaunchKernelGGL(kscores2, dim3(4096), dim3(256), 0, stream,
                     Bt, Ab, Up, VmT, aW2, ab2, scores, wsMin);
  hipLaunchKernelGGL(ksoftmax, dim3(512), dim3(256), 0, stream,
                     mask, wsMin, wsFlag, scores, prob);
  // msgT[q][d] = prob @ source^T  -> catT[:, 256:]
  hipLaunchKernelGGL((gemm_k<1, 16>), dim3(32), dim3(256), 0, stream,
                     prob, 512, srcbf, 512, (const float*)nullptr, (void*)(catT + 256), 512, 4);
  // h2T[q][o] = relu(catT @ mW1^T + mb1)
  hipLaunchKernelGGL((gemm_k<7, 16>), dim3(64), dim3(256), 0, stream,
                     catT, 512, mW1b, 512, mb1, (void*)h2T, 512, 8);
  // out[o2][q] = mW2 @ h2 + mb2
  hipLaunchKernelGGL((gemm_k<8, 16>), dim3(32), dim3(256), 0, stream,
                     mW2b, 512, h2T, 512, mb2, (void*)outMain, 512, 8);
}